// Round 6
// baseline (5896.551 us; speedup 1.0000x reference)
//
#include <hip/hip_runtime.h>
#include <stdint.h>

#define V 4096
#define D 128
#define E 12288
#define NPAD 16384
#define HALF 8192
#define TARGET 2048
#define MAXM (V - TARGET)    // 2048 max merges
#define ROWU32 256           // 4096 fields * 2 bits = 256 u32 per row (1 KB)
#define CAP 32               // candidates decided per round (all of them, exactly)

// s_waitcnt imms (gfx9): bits 3:0 vmcnt lo, 6:4 expcnt, 11:8 lgkmcnt, 15:14 vmcnt hi
#define WAIT_VM0   0x0F70    // vmcnt(0) only

// ws layout (bytes)
#define WS_N      0u                            // V*ROWU32*4 = 4 MB (2-bit matrix)
#define WS_PRI    (V * ROWU32 * 4u)             // V float
#define WS_KEYS   (WS_PRI + V * 4u)             // NPAD u64
#define WS_PK     (WS_KEYS + NPAD * 8u)         // E u32 (sorted packed edges)
#define WS_PAIRS  (WS_PK + E * 4u)              // MAXM u32
#define WS_MCOUNT (WS_PAIRS + MAXM * 4u)        // 1 int
#define WS_ALIVE  (WS_MCOUNT + 16u)             // V u8

typedef const __attribute__((address_space(1))) unsigned* gas1_t;
typedef __attribute__((address_space(3))) unsigned* las3_t;

__device__ __forceinline__ unsigned getf(const uint4& r, int c) {
    unsigned lo = (c & 2) ? r.z : r.x;
    unsigned hi = (c & 2) ? r.w : r.y;
    return (c & 1) ? hi : lo;
}
__device__ __forceinline__ void andf(uint4& r, int c, unsigned msk) {
    if (c == 0) r.x &= msk; else if (c == 1) r.y &= msk;
    else if (c == 2) r.z &= msk; else r.w &= msk;
}
__device__ __forceinline__ void orf(uint4& r, int c, unsigned v) {
    if (c == 0) r.x |= v; else if (c == 1) r.y |= v;
    else if (c == 2) r.z |= v; else r.w |= v;
}

// 2-bit field helpers on the 4-word register row M0..M3 (static word select)
#define MGETL(i, dst) { unsigned _w = ((i)<16)?M0:((i)<32)?M1:((i)<48)?M2:M3; \
                        dst = (_w >> (((i)&15)*2)) & 3u; }
#define MZERO(i) { unsigned _mz = ~(3u << (((i)&15)*2)); \
                   if ((i)<16) M0 &= _mz; else if ((i)<32) M1 &= _mz; \
                   else if ((i)<48) M2 &= _mz; else M3 &= _mz; }
#define MSET(i, v) { MZERO(i); unsigned _vv = ((unsigned)(v)) << (((i)&15)*2); \
                     if ((i)<16) M0 |= _vv; else if ((i)<32) M1 |= _vv; \
                     else if ((i)<48) M2 |= _vv; else M3 |= _vv; }

__global__ void k_scatter(const int* __restrict__ edges, unsigned* __restrict__ n32) {
    int e = blockIdx.x * 256 + threadIdx.x;
    if (e < E) {
        int a = edges[e], b = edges[E + e];
        atomicOr(&n32[a * ROWU32 + (b >> 4)], 2u << ((b & 15) * 2));
        atomicOr(&n32[b * ROWU32 + (a >> 4)], 2u << ((a & 15) * 2));
    }
}

// numpy pairwise f32 sum for n=128 (matches np oracle reduction order)
__global__ void k_pri(const float* __restrict__ f, float* __restrict__ pri) {
    int v = blockIdx.x * 256 + threadIdx.x;
    if (v < V) {
        const float* p = f + v * D;
        float r[8];
#pragma unroll
        for (int j = 0; j < 8; j++) r[j] = __fmul_rn(p[j], p[j]);
        for (int i = 8; i < D; i += 8) {
#pragma unroll
            for (int j = 0; j < 8; j++)
                r[j] = __fadd_rn(r[j], __fmul_rn(p[i + j], p[i + j]));
        }
        float s01 = __fadd_rn(r[0], r[1]);
        float s23 = __fadd_rn(r[2], r[3]);
        float s45 = __fadd_rn(r[4], r[5]);
        float s67 = __fadd_rn(r[6], r[7]);
        pri[v] = __fadd_rn(__fadd_rn(s01, s23), __fadd_rn(s45, s67));
    }
}

__global__ void k_keys(const int* __restrict__ edges, const float* __restrict__ pri,
                       unsigned long long* __restrict__ keys) {
    int s = blockIdx.x * 256 + threadIdx.x;
    if (s < NPAD) {
        unsigned long long rec;
        if (s < E) {
            int a = edges[s], b = edges[E + s];
            float k = __fadd_rn(pri[a], pri[b]);   // epri >= 0 -> bits monotone
            rec = ((unsigned long long)__float_as_uint(k) << 32) | (unsigned)s;
        } else {
            rec = (0xFFFFFFFFull << 32) | (unsigned)s;
        }
        keys[s] = rec;
    }
}

// bitonic sort one 8192-element half in LDS; 2 blocks run concurrently
__launch_bounds__(1024)
__global__ void k_sort2(unsigned long long* __restrict__ keys) {
    __shared__ unsigned long long srt[HALF];
    const int tid = threadIdx.x;
    unsigned long long* base = keys + blockIdx.x * HALF;
    for (int s = tid; s < HALF; s += 1024) srt[s] = base[s];
    __syncthreads();
    for (int k = 2; k <= HALF; k <<= 1) {
        for (int j = k >> 1; j >= 1; j >>= 1) {
            for (int i = tid; i < HALF; i += 1024) {
                int ixj = i ^ j;
                if (ixj > i) {
                    unsigned long long x = srt[i], y = srt[ixj];
                    bool up = ((i & k) == 0);
                    if ((x > y) == up) { srt[i] = y; srt[ixj] = x; }
                }
            }
            __syncthreads();
        }
    }
    for (int s = tid; s < HALF; s += 1024) base[s] = srt[s];
}

// merge-path the two sorted halves; emit packed (v0<<16|v1) in global order
__launch_bounds__(64)
__global__ void k_mergepath(const unsigned long long* __restrict__ keys,
                            const int* __restrict__ edges, unsigned* __restrict__ pkG) {
    int t = blockIdx.x * 64 + threadIdx.x;
    if (t >= E / 64) return;
    const unsigned long long* A = keys;
    const unsigned long long* B = keys + HALF;
    int d = t * 64;
    int lo = d > HALF ? d - HALF : 0;
    int hi = d < HALF ? d : HALF;
    while (lo < hi) {
        int mid = (lo + hi) >> 1;
        if (A[mid] < B[d - 1 - mid]) lo = mid + 1; else hi = mid;
    }
    int ia = lo, ib = d - lo;
    for (int o = d; o < d + 64; o++) {
        bool takeA = (ib >= HALF) || (ia < HALF && A[ia] < B[ib]);
        unsigned long long r = takeA ? A[ia++] : B[ib++];
        int e = (int)(r & 0xFFFFFFFFull);
        int a = edges[e], b = edges[E + e];
        pkG[o] = ((unsigned)a << 16) | (unsigned)b;
    }
}

// ONE wave: candidate pool + FULL-EXACT round decisions via register submatrix
// machine. Per round: select first 32 undecided (priority order), dedupe their
// <=64 endpoints to slots (lane==slot), fetch those rows to LDS, gather the
// UxU 2-bit submatrix into registers (one row per lane), then run the oracle
// sequentially over all 32 candidates in registers (shfl+VALU only): every
// candidate gets its exact final decision, INCLUDING chains into the same
// survivor. Apply kept merges serially on LDS rows (b128 ops); submatrix
// columns of written rows are patched from machine output; out-of-submatrix
// columns get atomicXor deltas; alive non-written submatrix rows get a
// Minit^Mfinal XOR pass. Rounds <= E/32 = 384 by construction.
__launch_bounds__(64, 1)
__global__ void k_collapse(const unsigned* __restrict__ pkG, unsigned* n32,
                           unsigned* __restrict__ pairsG, int* __restrict__ mcountG,
                           uint8_t* __restrict__ aliveG, float* __restrict__ out) {
    __shared__ unsigned shRows[64 * ROWU32];        // 64 KB: slot s (=lane) -> row
    __shared__ uint8_t  alive[V];                   // 4 KB
    __shared__ uint8_t  shV2S[V];                   // 4 KB vertex->slot (round-local)
    __shared__ unsigned shCand[CAP];
    __shared__ unsigned shUV[64];                   // slot -> vertex
    __shared__ uint8_t  shCS[2 * CAP];              // candidate endpoint -> slot
    __shared__ unsigned shM[64 * 4];                // machine final rows
    const int lane = threadIdx.x;
    for (int v = lane; v < V; v += 64) { alive[v] = 1; shV2S[v] = 0xFF; }
    __syncthreads();

    int cnt = V, mcount = 0, head = 64;
    unsigned pkv = pkG[lane];                       // pool: one candidate per lane
    bool dec = false;

    while (true) {
        const int a = (int)(pkv >> 16), b = (int)(pkv & 0xFFFFu);
        if (!dec && !(alive[a] && alive[b])) dec = true;
        __builtin_amdgcn_s_waitcnt(WAIT_VM0);        // prior round's stores visible
        if (!dec) {
            unsigned wv = *(volatile unsigned*)(n32 + a * ROWU32 + (b >> 4));
            if (((wv >> ((b & 15) * 2)) & 3u) != 2u) dec = true;  // 3 absorbing
        }
        unsigned long long mF = __ballot(!dec);

        if (mF) {
            int flagged = (int)__popcll(mF);
            int nacc = flagged < CAP ? flagged : CAP;
            int myK = -1;
            if (!dec) {
                int rank = (int)__popcll(mF & ((1ull << lane) - 1ull));
                if (rank < CAP) { myK = rank; shCand[rank] = pkv; }
            }
            __syncthreads();
            unsigned myCp = (lane < nacc) ? shCand[lane] : 0u;

            // ---- DEDUPE endpoints -> slots 0..U-1 ----
            int ev = -1;
            if (lane < 2 * nacc) {
                unsigned cp = shCand[lane >> 1];
                ev = (lane & 1) ? (int)(cp & 0xFFFFu) : (int)(cp >> 16);
                shV2S[ev] = (uint8_t)lane;           // last-writer wins
            }
            __syncthreads();
            bool primary = (ev >= 0) && (shV2S[ev] == (uint8_t)lane);
            unsigned long long pm = __ballot(primary);
            const int U = (int)__popcll(pm);
            if (primary) {
                int slot = (int)__popcll(pm & ((1ull << lane) - 1ull));
                shUV[slot] = (unsigned)ev;
                shV2S[ev] = (uint8_t)slot;
            }
            __syncthreads();
            if (lane < 2 * nacc) shCS[lane] = shV2S[ev];
            __syncthreads();
            unsigned myUV = (lane < U) ? shUV[lane] : 0u;
            unsigned csPack = 0u;
            if (lane < nacc) csPack = ((unsigned)shCS[2 * lane] << 8) | shCS[2 * lane + 1];

            // ---- FETCH the U unique rows to LDS (slot == lane index) ----
            for (int s = 0; s < U; s++) {
                int vv = __shfl((int)myUV, s);
                __builtin_amdgcn_global_load_lds(
                    (gas1_t)(n32 + vv * ROWU32 + lane * 4),
                    (las3_t)(shRows + s * ROWU32), 16, 0, 0);
            }
            __builtin_amdgcn_s_waitcnt(WAIT_VM0);
            __syncthreads();

            // ---- GATHER UxU submatrix: lane s holds row s (rotated y order
            // spreads LDS banks); also build ymask (submatrix cols in my
            // 64-field global window) ----
            unsigned M0 = 0u, M1 = 0u, M2 = 0u, M3 = 0u;
            unsigned long long ymask = 0ull;
            int y = lane; while (y >= U) y -= U;
            for (int t = 0; t < U; t++) {
                int uy = __shfl((int)myUV, y);       // per-lane src: ds_bpermute
                if ((uy >> 6) == lane) ymask |= 1ull << y;
                if (lane < U) {
                    unsigned wv = shRows[lane * ROWU32 + (uy >> 4)];
                    unsigned f = (wv >> ((uy & 15) * 2)) & 3u;
                    unsigned vv2 = f << ((y & 15) * 2);
                    if (y < 16) M0 |= vv2; else if (y < 32) M1 |= vv2;
                    else if (y < 48) M2 |= vv2; else M3 |= vv2;
                }
                y++; if (y == U) y = 0;
            }
            const unsigned Mi0 = M0, Mi1 = M1, Mi2 = M2, Mi3 = M3;

            // ---- MACHINE: exact oracle over all nacc candidates (registers) ----
            unsigned long long aliveS = (U >= 64) ? ~0ull : ((1ull << U) - 1ull);
            unsigned kept = 0u;
            int m = 0;
            const int limit = cnt - TARGET;          // >= 1 here
            bool limitHit = false;
            for (int k = 0; k < nacc; k++) {
                int cs = __shfl((int)csPack, k);
                const int s0 = (cs >> 8) & 0xFF, s1 = cs & 0xFF;
                unsigned w0 = (unsigned)__shfl((int)M0, s0);
                unsigned w1 = (unsigned)__shfl((int)M1, s0);
                unsigned w2 = (unsigned)__shfl((int)M2, s0);
                unsigned w3 = (unsigned)__shfl((int)M3, s0);
                unsigned wsel = (s1 < 16) ? w0 : (s1 < 32) ? w1 : (s1 < 48) ? w2 : w3;
                unsigned f = (wsel >> ((s1 & 15) * 2)) & 3u;
                bool ok = !limitHit && ((aliveS >> s0) & 1ull) &&
                          ((aliveS >> s1) & 1ull) && (f == 2u);
                if (ok) {
                    kept |= 1u << k; m++;
                    if (m == limit) limitHit = true;
                    unsigned r0 = (unsigned)__shfl((int)M0, s1);
                    unsigned r1 = (unsigned)__shfl((int)M1, s1);
                    unsigned r2 = (unsigned)__shfl((int)M2, s1);
                    unsigned r3 = (unsigned)__shfl((int)M3, s1);
                    if (lane == s0) {                // row s0 += row s1 (sat)
                        M0 = M0 | r0 | ((M0 & r0 & 0xAAAAAAAAu) >> 1);
                        M1 = M1 | r1 | ((M1 & r1 & 0xAAAAAAAAu) >> 1);
                        M2 = M2 | r2 | ((M2 & r2 & 0xAAAAAAAAu) >> 1);
                        M3 = M3 | r3 | ((M3 & r3 & 0xAAAAAAAAu) >> 1);
                        MZERO(s0); MZERO(s1);        // diag zeroes
                    }
                    {   // col op (all lanes): field[s0]=sat(f0+f1), field[s1]=0
                        unsigned f0, f1;
                        MGETL(s0, f0); MGETL(s1, f1);
                        unsigned nf = f0 | f1 | ((f0 & f1 & 2u) >> 1);
                        MSET(s0, nf); MZERO(s1);
                    }
                    if (lane == s1) { M0 = 0u; M1 = 0u; M2 = 0u; M3 = 0u; }
                    aliveS &= ~(1ull << s1);
                }
            }
            if (myK >= 0) dec = true;                // every selected is decided

            // ---- dump machine rows + MARK ----
            if (lane < U) {
                shM[lane * 4 + 0] = M0; shM[lane * 4 + 1] = M1;
                shM[lane * 4 + 2] = M2; shM[lane * 4 + 3] = M3;
            }
            if (lane < nacc && ((kept >> lane) & 1u)) {
                alive[(int)(myCp & 0xFFFFu)] = 0;
                int r = __popc(kept & ((1u << lane) - 1u));
                pairsG[mcount + r] = myCp;
            }
            mcount += m; cnt -= m;
            __syncthreads();
            if (cnt == TARGET) break;                // matrix no longer needed

            // ---- APPLY kept merges serially on LDS rows ----
            unsigned long long wbMask = 0ull;
            unsigned kmIter = kept;
            while (kmIter) {
                int k = __ffs(kmIter) - 1; kmIter &= kmIter - 1u;
                int cs = __shfl((int)csPack, k);
                const int s0 = (cs >> 8) & 0xFF, s1 = cs & 0xFF;
                unsigned cp = (unsigned)__shfl((int)myCp, k);
                const int v0 = (int)(cp >> 16), v1 = (int)(cp & 0xFFFFu);
                wbMask |= 1ull << s0;
                uint4 ra = ((const uint4*)(shRows + s0 * ROWU32))[lane];
                uint4 rb = ((const uint4*)(shRows + s1 * ROWU32))[lane];
                uint4 rr;
                rr.x = ra.x | rb.x | ((ra.x & rb.x & 0xAAAAAAAAu) >> 1);
                rr.y = ra.y | rb.y | ((ra.y & rb.y & 0xAAAAAAAAu) >> 1);
                rr.z = ra.z | rb.z | ((ra.z & rb.z & 0xAAAAAAAAu) >> 1);
                rr.w = ra.w | rb.w | ((ra.w & rb.w & 0xAAAAAAAAu) >> 1);
                if ((v0 >> 6) == lane) andf(rr, (v0 >> 4) & 3, ~(3u << ((v0 & 15) * 2)));
                if ((v1 >> 6) == lane) andf(rr, (v1 >> 4) & 3, ~(3u << ((v1 & 15) * 2)));
                ((uint4*)(shRows + s0 * ROWU32))[lane] = rr;
                // fixups for NON-submatrix neighbors of the dying row
                const int wi0 = v0 >> 4;
                const unsigned sh0 = (unsigned)((v0 & 15) * 2);
#pragma unroll
                for (int c2 = 0; c2 < 4; c2++) {
                    unsigned bb = getf(rb, c2);
                    if (!bb) continue;
                    unsigned aa = getf(ra, c2);
                    int xbase = (lane << 6) + (c2 << 4);
                    unsigned t2 = bb;
                    while (t2) {
                        int q = (__ffs(t2) - 1) >> 1;
                        t2 &= ~(3u << (q * 2));
                        int x = xbase + q;
                        if (x != v0 && x != v1 && shV2S[x] == 0xFF) {
                            unsigned a2 = (aa >> (q * 2)) & 3u;
                            unsigned b2 = (bb >> (q * 2)) & 3u;
                            unsigned n2 = a2 | b2 | ((a2 & b2 & 2u) >> 1);
                            unsigned dx = a2 ^ n2;
                            if (dx) atomicXor(n32 + x * ROWU32 + wi0, dx << sh0);
                        }
                    }
                }
            }
            __syncthreads();

            // ---- WRITEBACK surviving written rows (machine-patched cols) ----
            wbMask &= aliveS;                        // survivor died later: skip
            unsigned long long wm = wbMask;
            while (wm) {
                int s = __ffsll((long long)wm) - 1; wm &= wm - 1ull;
                int vv = __shfl((int)myUV, s);
                uint4 rr = ((const uint4*)(shRows + s * ROWU32))[lane];
                unsigned long long ym = ymask;
                while (ym) {                         // patch submatrix cols I own
                    int yy = __ffsll((long long)ym) - 1; ym &= ym - 1ull;
                    unsigned val = (shM[s * 4 + (yy >> 4)] >> ((yy & 15) * 2)) & 3u;
                    int uy = (int)shUV[yy];
                    int c = (uy >> 4) & 3;
                    unsigned sh = (unsigned)((uy & 15) * 2);
                    andf(rr, c, ~(3u << sh));
                    orf(rr, c, val << sh);
                }
                ((uint4*)(n32 + vv * ROWU32))[lane] = rr;
            }

            // ---- DIFF pass: alive, non-written submatrix rows -> XOR deltas ----
            if (lane < U && ((aliveS >> lane) & 1ull) && !((wbMask >> lane) & 1ull)) {
                const int myV = (int)myUV;
                unsigned d0 = M0 ^ Mi0, d1 = M1 ^ Mi1, d2 = M2 ^ Mi2, d3 = M3 ^ Mi3;
#define DIFFW(DW, WB) { unsigned _d = DW; while (_d) { \
                    int _q = (__ffs(_d) - 1) >> 1; \
                    unsigned _dx = (_d >> (_q * 2)) & 3u; \
                    _d &= ~(3u << (_q * 2)); \
                    int _uy = (int)shUV[WB + _q]; \
                    atomicXor(n32 + myV * ROWU32 + (_uy >> 4), \
                              _dx << ((_uy & 15) * 2)); } }
                DIFFW(d0, 0) DIFFW(d1, 16) DIFFW(d2, 32) DIFFW(d3, 48)
#undef DIFFW
            }
            __syncthreads();
            if (ev >= 0) shV2S[ev] = 0xFF;           // clear round-local map
            __syncthreads();
        } else {
            if (head >= E) break;                    // pool empty, stream done
        }

        // ---- COMPACT undecided to low lanes (order-preserving) + REFILL ----
        {
            unsigned long long mU = __ballot(!dec);
            int nU = (int)__popcll(mU);
            int p = 0;
#pragma unroll
            for (int step = 32; step; step >>= 1) {
                int c2 = p + step;
                unsigned long long pref =
                    (c2 >= 64) ? ~0ull : ((1ull << c2) - 1ull);
                if ((int)__popcll(mU & pref) <= lane) p = c2;
            }
            unsigned npkv = (unsigned)__shfl((int)pkv, p);
            if (lane < nU) { pkv = npkv; dec = false; }
            else {
                int idx = head + lane - nU;
                if (idx < E) { pkv = pkG[idx]; dec = false; }
                else dec = true;                     // inactive forever
            }
            head += 64 - nU;
        }
    }

    for (int v = lane; v < V; v += 64) {
        uint8_t ao = alive[v];
        aliveG[v] = ao;
        out[V * D + v] = ao ? 1.0f : 0.0f;
    }
    if (lane == 0) { mcountG[0] = mcount; out[V * D + V] = (float)cnt; }
}

// Replay merge forest: per-vertex (root, weight) then scatter-add w*f[v] into out[root].
__launch_bounds__(256)
__global__ void k_apply(const float* __restrict__ f, const unsigned* __restrict__ pairsG,
                        const int* __restrict__ mcountG, float* __restrict__ out) {
    __shared__ unsigned pl[MAXM];
    __shared__ int rootL[256];
    __shared__ float wL[256];
    const int tid = threadIdx.x;
    const int mc = mcountG[0];
    for (int j = tid; j < mc; j += 256) pl[j] = pairsG[j];
    __syncthreads();
    int cur = blockIdx.x * 256 + tid;
    float w = 1.0f;
    for (int j = 0; j < mc; j++) {
        unsigned p = pl[j];
        int v0 = (int)(p >> 16), v1 = (int)(p & 0xFFFFu);
        if (cur == v1) { cur = v0; w *= 0.5f; }
        else if (cur == v0) w *= 0.5f;
    }
    rootL[tid] = cur;
    wL[tid] = w;
    __syncthreads();
    const int sub = tid >> 7;
    const int d = tid & 127;
    for (int s = 0; s < 256; s += 2) {
        int idx = s + sub;
        int vv = blockIdx.x * 256 + idx;
        atomicAdd(&out[rootL[idx] * D + d], wL[idx] * f[vv * D + d]);
    }
}

extern "C" void kernel_launch(void* const* d_in, const int* in_sizes, int n_in,
                              void* d_out, int out_size, void* d_ws, size_t ws_size,
                              hipStream_t stream) {
    (void)in_sizes; (void)n_in; (void)out_size; (void)ws_size;
    const float* features = (const float*)d_in[0];
    const int* edges = (const int*)d_in[1];
    uint8_t* ws = (uint8_t*)d_ws;
    unsigned* n32 = (unsigned*)(ws + WS_N);
    float* pri = (float*)(ws + WS_PRI);
    unsigned long long* keys = (unsigned long long*)(ws + WS_KEYS);
    unsigned* pkG = (unsigned*)(ws + WS_PK);
    unsigned* pairsG = (unsigned*)(ws + WS_PAIRS);
    int* mcountG = (int*)(ws + WS_MCOUNT);
    uint8_t* aliveG = ws + WS_ALIVE;
    float* out = (float*)d_out;

    hipMemsetAsync(n32, 0, (size_t)V * ROWU32 * 4, stream);
    hipMemsetAsync(out, 0, (size_t)V * D * sizeof(float), stream);
    k_pri<<<(V + 255) / 256, 256, 0, stream>>>(features, pri);
    k_scatter<<<(E + 255) / 256, 256, 0, stream>>>(edges, n32);
    k_keys<<<(NPAD + 255) / 256, 256, 0, stream>>>(edges, pri, keys);
    k_sort2<<<2, 1024, 0, stream>>>(keys);
    k_mergepath<<<(E / 64 + 63) / 64, 64, 0, stream>>>(keys, edges, pkG);
    k_collapse<<<1, 64, 0, stream>>>(pkG, n32, pairsG, mcountG, aliveG, out);
    k_apply<<<V / 256, 256, 0, stream>>>(features, pairsG, mcountG, out);
}

// Round 7
// 3756.800 us; speedup vs baseline: 1.5696x; 1.5696x over previous
//
#include <hip/hip_runtime.h>
#include <stdint.h>

#define V 4096
#define D 128
#define E 12288
#define NPAD 16384
#define HALF 8192
#define TARGET 2048
#define MAXM (V - TARGET)    // 2048 max merges
#define ROWU32 256           // 4096 fields * 2 bits = 256 u32 per row (1 KB)
#define CAP 16               // max accepts per round (R0-proven)
#define NPAIR 16             // stable row-slot pairs (2 rows each) -> 32 KB

// s_waitcnt imms (gfx9): bits 3:0 vmcnt lo, 6:4 expcnt, 11:8 lgkmcnt, 15:14 vmcnt hi
#define WAIT_VM0   0x0F70    // vmcnt(0) only

// ws layout (bytes)
#define WS_N      0u                            // V*ROWU32*4 = 4 MB (2-bit matrix)
#define WS_PRI    (V * ROWU32 * 4u)             // V float
#define WS_KEYS   (WS_PRI + V * 4u)             // NPAD u64
#define WS_PK     (WS_KEYS + NPAD * 8u)         // E u32 (sorted packed edges)
#define WS_PAIRS  (WS_PK + E * 4u)              // MAXM u32
#define WS_MCOUNT (WS_PAIRS + MAXM * 4u)        // 1 int
#define WS_ALIVE  (WS_MCOUNT + 16u)             // V u8

typedef const __attribute__((address_space(1))) unsigned* gas1_t;
typedef __attribute__((address_space(3))) unsigned* las3_t;

__device__ __forceinline__ unsigned getf(const uint4& r, int c) {
    unsigned lo = (c & 2) ? r.z : r.x;
    unsigned hi = (c & 2) ? r.w : r.y;
    return (c & 1) ? hi : lo;
}
__device__ __forceinline__ void andf(uint4& r, int c, unsigned msk) {
    if (c == 0) r.x &= msk; else if (c == 1) r.y &= msk;
    else if (c == 2) r.z &= msk; else r.w &= msk;
}
__device__ __forceinline__ unsigned wave_or32(unsigned v) {
#pragma unroll
    for (int o = 32; o; o >>= 1) v |= (unsigned)__shfl_xor((int)v, o);
    return v;
}

__global__ void k_scatter(const int* __restrict__ edges, unsigned* __restrict__ n32) {
    int e = blockIdx.x * 256 + threadIdx.x;
    if (e < E) {
        int a = edges[e], b = edges[E + e];
        atomicOr(&n32[a * ROWU32 + (b >> 4)], 2u << ((b & 15) * 2));
        atomicOr(&n32[b * ROWU32 + (a >> 4)], 2u << ((a & 15) * 2));
    }
}

// numpy pairwise f32 sum for n=128 (matches np oracle reduction order)
__global__ void k_pri(const float* __restrict__ f, float* __restrict__ pri) {
    int v = blockIdx.x * 256 + threadIdx.x;
    if (v < V) {
        const float* p = f + v * D;
        float r[8];
#pragma unroll
        for (int j = 0; j < 8; j++) r[j] = __fmul_rn(p[j], p[j]);
        for (int i = 8; i < D; i += 8) {
#pragma unroll
            for (int j = 0; j < 8; j++)
                r[j] = __fadd_rn(r[j], __fmul_rn(p[i + j], p[i + j]));
        }
        float s01 = __fadd_rn(r[0], r[1]);
        float s23 = __fadd_rn(r[2], r[3]);
        float s45 = __fadd_rn(r[4], r[5]);
        float s67 = __fadd_rn(r[6], r[7]);
        pri[v] = __fadd_rn(__fadd_rn(s01, s23), __fadd_rn(s45, s67));
    }
}

__global__ void k_keys(const int* __restrict__ edges, const float* __restrict__ pri,
                       unsigned long long* __restrict__ keys) {
    int s = blockIdx.x * 256 + threadIdx.x;
    if (s < NPAD) {
        unsigned long long rec;
        if (s < E) {
            int a = edges[s], b = edges[E + s];
            float k = __fadd_rn(pri[a], pri[b]);   // epri >= 0 -> bits monotone
            rec = ((unsigned long long)__float_as_uint(k) << 32) | (unsigned)s;
        } else {
            rec = (0xFFFFFFFFull << 32) | (unsigned)s;
        }
        keys[s] = rec;
    }
}

// bitonic sort one 8192-element half in LDS; 2 blocks run concurrently
__launch_bounds__(1024)
__global__ void k_sort2(unsigned long long* __restrict__ keys) {
    __shared__ unsigned long long srt[HALF];
    const int tid = threadIdx.x;
    unsigned long long* base = keys + blockIdx.x * HALF;
    for (int s = tid; s < HALF; s += 1024) srt[s] = base[s];
    __syncthreads();
    for (int k = 2; k <= HALF; k <<= 1) {
        for (int j = k >> 1; j >= 1; j >>= 1) {
            for (int i = tid; i < HALF; i += 1024) {
                int ixj = i ^ j;
                if (ixj > i) {
                    unsigned long long x = srt[i], y = srt[ixj];
                    bool up = ((i & k) == 0);
                    if ((x > y) == up) { srt[i] = y; srt[ixj] = x; }
                }
            }
            __syncthreads();
        }
    }
    for (int s = tid; s < HALF; s += 1024) base[s] = srt[s];
}

// merge-path the two sorted halves; emit packed (v0<<16|v1) in global order
__launch_bounds__(64)
__global__ void k_mergepath(const unsigned long long* __restrict__ keys,
                            const int* __restrict__ edges, unsigned* __restrict__ pkG) {
    int t = blockIdx.x * 64 + threadIdx.x;
    if (t >= E / 64) return;
    const unsigned long long* A = keys;
    const unsigned long long* B = keys + HALF;
    int d = t * 64;
    int lo = d > HALF ? d - HALF : 0;
    int hi = d < HALF ? d : HALF;
    while (lo < hi) {
        int mid = (lo + hi) >> 1;
        if (A[mid] < B[d - 1 - mid]) lo = mid + 1; else hi = mid;
    }
    int ia = lo, ib = d - lo;
    for (int o = d; o < d + 64; o++) {
        bool takeA = (ib >= HALF) || (ia < HALF && A[ia] < B[ib]);
        unsigned long long r = takeA ? A[ia++] : B[ib++];
        int e = (int)(r & 0xFFFFFFFFull);
        int a = edges[e], b = edges[E + e];
        pkG[o] = ((unsigned)a << 16) | (unsigned)b;
    }
}

// ONE wave: R0 window structure + STABLE SLOT-PAIR row cache + DEAD refinement.
// A lane claims a slot-pair (2 rows) on first selection and KEEPS it across
// retry rounds (no rank-keyed reshuffle, no vertex maps). Rows are refetched
// only when provably touched by a kept merge: endpoint identity with
// {v0k,v1k}, or own-row field at v1k != 0 (the exact fixup trigger). fv is a
// register, invalidated only on {a,b} n {keptV0} != 0 (R0's refresh rule).
// Rounds where no kept merge touches any pool lane skip BOTH vmcnt drains and
// all fetches. Filter/greedy/apply semantics are exactly R0 + DEAD (dead
// candidates never block; sequence-exact since the oracle rejects them too).
__launch_bounds__(64, 1)
__global__ void k_collapse(const unsigned* __restrict__ pkG, unsigned* n32,
                           unsigned* __restrict__ pairsG, int* __restrict__ mcountG,
                           uint8_t* __restrict__ aliveG, float* __restrict__ out) {
    __shared__ unsigned shRows[2 * NPAIR * ROWU32];  // 32 KB: pair p -> rows 2p,2p+1
    __shared__ uint8_t  alive[V];                    // 4 KB
    __shared__ unsigned shCand[CAP];
    __shared__ unsigned shConf[CAP];                 // conflict mask (bits j<k)
    __shared__ unsigned shDeadM[CAP];                // "j's v1 kills k" mask
    __shared__ uint8_t  shCS[2 * CAP];               // rank -> row indices
    const int lane = threadIdx.x;
    for (int v = lane; v < V; v += 64) alive[v] = 1;
    __syncthreads();

    int cnt = V, mcount = 0;
    bool done = false;
    unsigned freeMask = 0xFFFFu;                     // uniform slot-pair free mask
    bool hasSlot = false, rowsStale = false;
    int ownPair = 0;

    for (int w = 0; w < E && !done; w += 64) {
        unsigned pkv = pkG[w + lane];
        const int a = (int)(pkv >> 16), b = (int)(pkv & 0xFFFFu);
        bool dec = !(alive[a] && alive[b]);          // monotone: false is final
        bool fvKnown = false;
        unsigned fv = 0u;

        while (!done) {
            // ---- TOP: resolve unknown fv (one shared drain, only if needed) ----
            bool needF = !dec && !fvKnown;
            if (__ballot(needF)) {
                __builtin_amdgcn_s_waitcnt(WAIT_VM0);
                if (needF) {
                    unsigned wv = *(volatile unsigned*)(n32 + a * ROWU32 + (b >> 4));
                    fv = (wv >> ((b & 15) * 2)) & 3u;
                    fvKnown = true;
                }
            }
            if (!dec && fv != 2u) dec = true;         // monotone reject (final)

            // ---- free slot-pairs of decided holders (uniform register update) ----
            {
                unsigned fb = (dec && hasSlot) ? (1u << ownPair) : 0u;
                fb = wave_or32(fb);
                freeMask |= fb;
                if (dec) hasSlot = false;
            }

            unsigned long long mF = __ballot(!dec);
            if (!mF) break;

            int limit = cnt - TARGET; if (limit > CAP) limit = CAP;
            const unsigned long long below = (1ull << lane) - 1ull;
            int rank = (int)__popcll(mF & below);
            bool sel0 = !dec && (rank < limit);

            // ---- CLAIM slot-pairs (attempt 2 frees idle holders on shortage) ----
            bool needClaim = sel0 && !hasSlot;
            for (int attempt = 0; attempt < 2; attempt++) {
                unsigned long long cm = __ballot(needClaim);
                if (!cm) break;
                int ci = (int)__popcll(cm & below);
                int avail = __popc(freeMask);
                unsigned cb = 0u;
                if (needClaim && ci < avail) {
                    unsigned t = freeMask;
                    for (int q = 0; q < ci; q++) t &= t - 1u;   // ci-th free pair
                    ownPair = __ffs(t) - 1;
                    hasSlot = true; rowsStale = true; needClaim = false;
                    cb = 1u << ownPair;
                }
                cb = wave_or32(cb);
                freeMask &= ~cb;
                if (__ballot(needClaim)) {            // shortage: evict idle holders
                    unsigned fb = (!sel0 && hasSlot) ? (1u << ownPair) : 0u;
                    fb = wave_or32(fb);
                    freeMask |= fb;
                    if (!sel0 && hasSlot) hasSlot = false;
                } else break;
            }
            bool sel = sel0 && hasSlot;               // claim always succeeds by att.2
            unsigned long long selm = __ballot(sel);
            int nacc = (int)__popcll(selm);
            int myK = sel ? (int)__popcll(selm & below) : -1;
            if (sel) {
                shCand[myK] = pkv;
                shCS[2 * myK] = (uint8_t)(2 * ownPair);
                shCS[2 * myK + 1] = (uint8_t)(2 * ownPair + 1);
            }
            if (lane < CAP) { shConf[lane] = 0u; shDeadM[lane] = 0u; }

            // ---- FETCH only new/stale selected rows (skip drains when none) ----
            unsigned long long fm2 = __ballot(sel && rowsStale);
            if (fm2) {
                __builtin_amdgcn_s_waitcnt(WAIT_VM0);    // prior stores visible
                unsigned long long t = fm2;
                while (t) {
                    int l = __ffsll((long long)t) - 1; t &= t - 1ull;
                    int aL = __shfl(a, l);
                    int bL = __shfl(b, l);
                    int pr = __shfl(ownPair, l);
                    __builtin_amdgcn_global_load_lds(
                        (gas1_t)(n32 + aL * ROWU32 + lane * 4),
                        (las3_t)(shRows + (2 * pr) * ROWU32), 16, 0, 0);
                    __builtin_amdgcn_global_load_lds(
                        (gas1_t)(n32 + bL * ROWU32 + lane * 4),
                        (las3_t)(shRows + (2 * pr + 1) * ROWU32), 16, 0, 0);
                }
                __builtin_amdgcn_s_waitcnt(WAIT_VM0);
                if (sel) rowsStale = false;
            }
            __syncthreads();

            // ---- FILTER: pairwise (j<k) conflicts (R0 H1/H2) + dkill ----
            for (int pp = lane; pp < CAP * CAP; pp += 64) {
                int k = pp >> 4, j = pp & 15;
                if (j < k && k < nacc) {
                    unsigned cj = shCand[j], ck = shCand[k];
                    int v0j = (int)(cj >> 16), v1j = (int)(cj & 0xFFFFu);
                    int v0k = (int)(ck >> 16), v1k = (int)(ck & 0xFFFFu);
                    bool dkill = (v0k == v1j) || (v1k == v1j);
                    bool c = dkill || (v0k == v0j) || (v1k == v0j);
                    const unsigned* rBj = shRows + (int)shCS[2 * j + 1] * ROWU32;
                    const unsigned* rBk = shRows + (int)shCS[2 * k + 1] * ROWU32;
                    // H1: {v0k,v1k} adjacent to v1j
                    c |= ((rBj[v0k >> 4] >> ((v0k & 15) * 2)) & 3u) != 0u;
                    c |= ((rBj[v1k >> 4] >> ((v1k & 15) * 2)) & 3u) != 0u;
                    // H2: v0j adjacent to v1k
                    c |= ((rBk[v0j >> 4] >> ((v0j & 15) * 2)) & 3u) != 0u;
                    if (c) atomicOr(&shConf[k], 1u << j);
                    if (dkill) atomicOr(&shDeadM[k], 1u << j);
                }
            }
            __syncthreads();

            // ---- GREEDY keep (replicated VALU) with DEAD refinement ----
            unsigned kept = 0u, blocked = 0u, deadm = 0u;
            for (int k = 0; k < nacc; k++) {
                unsigned bit = 1u << k;
                if (shDeadM[k] & kept) { deadm |= bit; continue; }
                if (shConf[k] & (kept | blocked)) { blocked |= bit; continue; }
                kept |= bit;
            }
            int nk = __popc(kept);                   // >=1: k=0 has empty row
            if (myK >= 0 && (((kept | deadm) >> myK) & 1u)) dec = true;

            // ---- MARK: alive + merge log (priority order) ----
            if (myK >= 0 && ((kept >> myK) & 1u)) {
                alive[b] = 0;                        // my v1 dies
                int r = __popc(kept & ((1u << myK) - 1u));
                pairsG[mcount + r] = pkv;
            }
            mcount += nk; cnt -= nk;
            __syncthreads();
            if (cnt == TARGET) { done = true; break; }   // matrix no longer needed

            // ---- APPLY: group g = lane>>2 applies kept candidate g (R0) ----
            {
                int g = lane >> 2, sub = lane & 3;
                if (g < nacc && ((kept >> g) & 1u)) {
                    unsigned cp = shCand[g];
                    int v0 = (int)(cp >> 16), v1 = (int)(cp & 0xFFFFu);
                    const uint4* rowA = (const uint4*)(shRows + (int)shCS[2*g] * ROWU32);
                    const uint4* rowB = (const uint4*)(shRows + (int)shCS[2*g+1] * ROWU32);
                    int m0u = v0 >> 6, m1u = v1 >> 6;
                    int sh0 = (v0 & 15) * 2, wi0 = v0 >> 4;
                    for (int t = 0; t < 16; t++) {
                        int u = sub * 16 + ((t + lane) & 15);   // bank-spread rotation
                        uint4 ra = rowA[u], rb = rowB[u];
                        uint4 rr;
                        rr.x = ra.x | rb.x | ((ra.x & rb.x & 0xAAAAAAAAu) >> 1);
                        rr.y = ra.y | rb.y | ((ra.y & rb.y & 0xAAAAAAAAu) >> 1);
                        rr.z = ra.z | rb.z | ((ra.z & rb.z & 0xAAAAAAAAu) >> 1);
                        rr.w = ra.w | rb.w | ((ra.w & rb.w & 0xAAAAAAAAu) >> 1);
                        if (u == m0u) andf(rr, (v0 >> 4) & 3, ~(3u << ((v0 & 15) * 2)));
                        if (u == m1u) andf(rr, (v1 >> 4) & 3, ~(3u << ((v1 & 15) * 2)));
                        ((uint4*)(n32 + v0 * ROWU32))[u] = rr;  // global writeback
                        // column fixups via atomicXor (symmetry gives old value)
#pragma unroll
                        for (int c = 0; c < 4; c++) {
                            unsigned bb = getf(rb, c);
                            if (!bb) continue;
                            unsigned aa = getf(ra, c), vvv = getf(rr, c);
                            int xbase = (u << 6) + (c << 4);
                            unsigned tt = bb;
                            while (tt) {
                                int q = (__ffs(tt) - 1) >> 1;
                                tt &= ~(3u << (q * 2));
                                int x = xbase + q;
                                if (x != v0 && x != v1) {
                                    unsigned dx =
                                        (((aa >> (q*2)) ^ (vvv >> (q*2))) & 3u) << sh0;
                                    if (dx) atomicXor(n32 + x * ROWU32 + wi0, dx);
                                }
                            }
                        }
                    }
                }
            }
            __syncthreads();

            // ---- STALE-SCAN + fv invalidation (exact touch rules) ----
            {
                unsigned km = kept;
                while (km) {
                    int k2 = __ffs(km) - 1; km &= km - 1u;
                    unsigned cp = shCand[k2];            // broadcast read
                    int v0k = (int)(cp >> 16), v1k = (int)(cp & 0xFFFFu);
                    if (!dec) {
                        if (a == v0k || b == v0k) fvKnown = false;
                        if (hasSlot && !rowsStale) {
                            if (a == v0k || b == v0k || a == v1k || b == v1k)
                                rowsStale = true;        // row rewritten / died
                            else {
                                // fixup trigger: my row adjacent to dying v1k
                                unsigned f1 = (shRows[(2*ownPair)*ROWU32 + (v1k>>4)]
                                               >> ((v1k & 15) * 2)) & 3u;
                                unsigned f2 = (shRows[(2*ownPair+1)*ROWU32 + (v1k>>4)]
                                               >> ((v1k & 15) * 2)) & 3u;
                                if (f1 | f2) rowsStale = true;
                            }
                        }
                    }
                }
            }
            __syncthreads();
        }
    }

    for (int v = lane; v < V; v += 64) {
        uint8_t ao = alive[v];
        aliveG[v] = ao;
        out[V * D + v] = ao ? 1.0f : 0.0f;
    }
    if (lane == 0) { mcountG[0] = mcount; out[V * D + V] = (float)cnt; }
}

// Replay merge forest: per-vertex (root, weight) then scatter-add w*f[v] into out[root].
__launch_bounds__(256)
__global__ void k_apply(const float* __restrict__ f, const unsigned* __restrict__ pairsG,
                        const int* __restrict__ mcountG, float* __restrict__ out) {
    __shared__ unsigned pl[MAXM];
    __shared__ int rootL[256];
    __shared__ float wL[256];
    const int tid = threadIdx.x;
    const int mc = mcountG[0];
    for (int j = tid; j < mc; j += 256) pl[j] = pairsG[j];
    __syncthreads();
    int cur = blockIdx.x * 256 + tid;
    float w = 1.0f;
    for (int j = 0; j < mc; j++) {
        unsigned p = pl[j];
        int v0 = (int)(p >> 16), v1 = (int)(p & 0xFFFFu);
        if (cur == v1) { cur = v0; w *= 0.5f; }
        else if (cur == v0) w *= 0.5f;
    }
    rootL[tid] = cur;
    wL[tid] = w;
    __syncthreads();
    const int sub = tid >> 7;
    const int d = tid & 127;
    for (int s = 0; s < 256; s += 2) {
        int idx = s + sub;
        int vv = blockIdx.x * 256 + idx;
        atomicAdd(&out[rootL[idx] * D + d], wL[idx] * f[vv * D + d]);
    }
}

extern "C" void kernel_launch(void* const* d_in, const int* in_sizes, int n_in,
                              void* d_out, int out_size, void* d_ws, size_t ws_size,
                              hipStream_t stream) {
    (void)in_sizes; (void)n_in; (void)out_size; (void)ws_size;
    const float* features = (const float*)d_in[0];
    const int* edges = (const int*)d_in[1];
    uint8_t* ws = (uint8_t*)d_ws;
    unsigned* n32 = (unsigned*)(ws + WS_N);
    float* pri = (float*)(ws + WS_PRI);
    unsigned long long* keys = (unsigned long long*)(ws + WS_KEYS);
    unsigned* pkG = (unsigned*)(ws + WS_PK);
    unsigned* pairsG = (unsigned*)(ws + WS_PAIRS);
    int* mcountG = (int*)(ws + WS_MCOUNT);
    uint8_t* aliveG = ws + WS_ALIVE;
    float* out = (float*)d_out;

    hipMemsetAsync(n32, 0, (size_t)V * ROWU32 * 4, stream);
    hipMemsetAsync(out, 0, (size_t)V * D * sizeof(float), stream);
    k_pri<<<(V + 255) / 256, 256, 0, stream>>>(features, pri);
    k_scatter<<<(E + 255) / 256, 256, 0, stream>>>(edges, n32);
    k_keys<<<(NPAD + 255) / 256, 256, 0, stream>>>(edges, pri, keys);
    k_sort2<<<2, 1024, 0, stream>>>(keys);
    k_mergepath<<<(E / 64 + 63) / 64, 64, 0, stream>>>(keys, edges, pkG);
    k_collapse<<<1, 64, 0, stream>>>(pkG, n32, pairsG, mcountG, aliveG, out);
    k_apply<<<V / 256, 256, 0, stream>>>(features, pairsG, mcountG, out);
}